// Round 1
// baseline (986.736 us; speedup 1.0000x reference)
//
#include <hip/hip_runtime.h>
#include <hip/hip_cooperative_groups.h>

namespace cg = cooperative_groups;

// B=64, L=4096, D=512, fp32.
// context[b,d] = (1/L) * sum_l softmax_l(energy[b,:]) * enc[b,l,d]
// energy[b,l]  = dot(h[b,:], enc[b,l,:])
//
// WORKSPACE-FREE version: the previous 2-pass kernel wrote partials to d_ws,
// and rocprof shows the timed graph dominated by 2-GiB fillBufferAligned
// dispatches (~330us each) re-poisoning that workspace. Here all cross-block
// state (2 floats per (b,chunk) = 2048 floats) transiently lives in `out`
// itself, synchronized with cooperative grid barriers; context partials are
// merged with device-scope atomicAdd. enc is still read exactly once.

#define D_DIM 512
#define B_DIM 64
#define L_DIM 4096
#define CCHUNK 16

__device__ __forceinline__ float dot8(const float4 h0, const float4 h1,
                                      const float4 v0, const float4 v1) {
    return h0.x * v0.x + h0.y * v0.y + h0.z * v0.z + h0.w * v0.w
         + h1.x * v1.x + h1.y * v1.y + h1.z * v1.z + h1.w * v1.w;
}

__global__ __launch_bounds__(256) void attn_fused_coop(
    const float* __restrict__ h,     // [B, D]
    const float* __restrict__ enc,   // [B, L, D]
    float* __restrict__ out)         // [B, D] (first 2048 floats used as scratch pre-sync)
{
    const int b    = blockIdx.y;
    const int c    = blockIdx.x;
    const int tid  = threadIdx.x;
    const int wave = tid >> 6;
    const int lane = tid & 63;

    constexpr int rowsPerBlock = L_DIM / CCHUNK;    // 256
    constexpr int rowsPerWave  = rowsPerBlock / 4;  // 64
    const int l0 = c * rowsPerBlock + wave * rowsPerWave;

    // h fragment: lane covers d = 4*lane..4*lane+3 and 256+4*lane..+3
    const float4* h4 = reinterpret_cast<const float4*>(h + (size_t)b * D_DIM);
    const float4 h0 = h4[lane];
    const float4 h1 = h4[lane + 64];

    const float* rowp = enc + ((size_t)b * L_DIM + (size_t)l0) * D_DIM + 4 * lane;

    float m = -3.0e38f;
    float s = 0.0f;
    float4 a0 = {0.f, 0.f, 0.f, 0.f};
    float4 a1 = {0.f, 0.f, 0.f, 0.f};

    float4 v0 = *reinterpret_cast<const float4*>(rowp);
    float4 v1 = *reinterpret_cast<const float4*>(rowp + 256);

    for (int r = 0; r < rowsPerWave; ++r) {
        // prefetch next row (clamped: last iter re-reads current row, L1-hit)
        const float* np = rowp + ((r + 1 < rowsPerWave) ? D_DIM : 0);
        const float4 nv0 = *reinterpret_cast<const float4*>(np);
        const float4 nv1 = *reinterpret_cast<const float4*>(np + 256);

        float e = dot8(h0, h1, v0, v1);
        #pragma unroll
        for (int off = 32; off > 0; off >>= 1)
            e += __shfl_xor(e, off, 64);
        // e is wave-uniform; branch below is wave-uniform (taken ~ln(rows) times)
        if (e > m) {
            const float alpha = __expf(m - e);
            s *= alpha;
            a0.x *= alpha; a0.y *= alpha; a0.z *= alpha; a0.w *= alpha;
            a1.x *= alpha; a1.y *= alpha; a1.z *= alpha; a1.w *= alpha;
            m = e;
        }
        const float w = __expf(e - m);
        s += w;
        a0.x += w * v0.x; a0.y += w * v0.y; a0.z += w * v0.z; a0.w += w * v0.w;
        a1.x += w * v1.x; a1.y += w * v1.y; a1.z += w * v1.z; a1.w += w * v1.w;

        v0 = nv0; v1 = nv1;
        rowp += D_DIM;
    }

    // ---- combine the 4 waves of this block in LDS ----
    __shared__ float sm_m[4];
    __shared__ float sm_s[4];
    __shared__ float sm_ctx[4][D_DIM];

    reinterpret_cast<float4*>(&sm_ctx[wave][0])[lane]   = a0;  // d = 4*lane
    reinterpret_cast<float4*>(&sm_ctx[wave][256])[lane] = a1;  // d = 256+4*lane
    if (lane == 0) { sm_m[wave] = m; sm_s[wave] = s; }
    __syncthreads();

    const float blkM = fmaxf(fmaxf(sm_m[0], sm_m[1]), fmaxf(sm_m[2], sm_m[3]));
    const float w0 = __expf(sm_m[0] - blkM);
    const float w1 = __expf(sm_m[1] - blkM);
    const float w2 = __expf(sm_m[2] - blkM);
    const float w3 = __expf(sm_m[3] - blkM);

    // fold the 4 wave partials into sm_ctx[0] (each thread owns disjoint d)
    for (int d = tid; d < D_DIM; d += 256) {
        sm_ctx[0][d] = sm_ctx[0][d] * w0 + sm_ctx[1][d] * w1
                     + sm_ctx[2][d] * w2 + sm_ctx[3][d] * w3;
    }
    if (tid == 0) {
        const float blkS = sm_s[0] * w0 + sm_s[1] * w1 + sm_s[2] * w2 + sm_s[3] * w3;
        float* scratch = out + (size_t)(b * CCHUNK + c) * 2;   // indices [0, 2048)
        scratch[0] = blkM;
        scratch[1] = blkS;
    }

    cg::grid_group g = cg::this_grid();
    g.sync();   // all (m,s) partials visible

    // ---- phase 2: every block derives its batch's global (M, S) ----
    __shared__ float s_scale;
    if (tid == 0) {
        float M = -3.0e38f;
        #pragma unroll
        for (int i = 0; i < CCHUNK; ++i)
            M = fmaxf(M, out[(size_t)(b * CCHUNK + i) * 2]);
        float S = 0.f;
        #pragma unroll
        for (int i = 0; i < CCHUNK; ++i)
            S += out[(size_t)(b * CCHUNK + i) * 2 + 1]
               * __expf(out[(size_t)(b * CCHUNK + i) * 2] - M);
        s_scale = __expf(blkM - M) / (S * (float)L_DIM);
    }
    __syncthreads();
    const float scale = s_scale;

    g.sync();   // all scratch READS done before anyone overwrites out

    // ---- phase 3: chunk 0 stores, then chunks 1..15 accumulate ----
    if (c == 0) {
        for (int d = tid; d < D_DIM; d += 256)
            out[(size_t)b * D_DIM + d] = scale * sm_ctx[0][d];
    }
    g.sync();   // base values in place before atomics
    if (c != 0) {
        for (int d = tid; d < D_DIM; d += 256)
            atomicAdd(&out[(size_t)b * D_DIM + d], scale * sm_ctx[0][d]);
    }
}

// Fallback: one block per batch, no cross-block communication, no workspace.
// Used only if the cooperative launch is rejected (e.g. under graph capture).
__global__ __launch_bounds__(1024) void attn_fallback(
    const float* __restrict__ h,
    const float* __restrict__ enc,
    float* __restrict__ out)
{
    const int b    = blockIdx.x;
    const int tid  = threadIdx.x;
    const int wave = tid >> 6;    // 0..15
    const int lane = tid & 63;

    constexpr int rowsPerWave = L_DIM / 16;  // 256
    const int l0 = wave * rowsPerWave;

    const float4* h4 = reinterpret_cast<const float4*>(h + (size_t)b * D_DIM);
    const float4 h0 = h4[lane];
    const float4 h1 = h4[lane + 64];

    const float* rowp = enc + ((size_t)b * L_DIM + (size_t)l0) * D_DIM + 4 * lane;

    float m = -3.0e38f;
    float s = 0.0f;
    float4 a0 = {0.f, 0.f, 0.f, 0.f};
    float4 a1 = {0.f, 0.f, 0.f, 0.f};

    float4 v0 = *reinterpret_cast<const float4*>(rowp);
    float4 v1 = *reinterpret_cast<const float4*>(rowp + 256);

    for (int r = 0; r < rowsPerWave; ++r) {
        const float* np = rowp + ((r + 1 < rowsPerWave) ? D_DIM : 0);
        const float4 nv0 = *reinterpret_cast<const float4*>(np);
        const float4 nv1 = *reinterpret_cast<const float4*>(np + 256);

        float e = dot8(h0, h1, v0, v1);
        #pragma unroll
        for (int off = 32; off > 0; off >>= 1)
            e += __shfl_xor(e, off, 64);
        if (e > m) {
            const float alpha = __expf(m - e);
            s *= alpha;
            a0.x *= alpha; a0.y *= alpha; a0.z *= alpha; a0.w *= alpha;
            a1.x *= alpha; a1.y *= alpha; a1.z *= alpha; a1.w *= alpha;
            m = e;
        }
        const float w = __expf(e - m);
        s += w;
        a0.x += w * v0.x; a0.y += w * v0.y; a0.z += w * v0.z; a0.w += w * v0.w;
        a1.x += w * v1.x; a1.y += w * v1.y; a1.z += w * v1.z; a1.w += w * v1.w;

        v0 = nv0; v1 = nv1;
        rowp += D_DIM;
    }

    __shared__ float sm_m[16];
    __shared__ float sm_s[16];
    __shared__ float sm_ctx[16][D_DIM];   // 32 KiB

    reinterpret_cast<float4*>(&sm_ctx[wave][0])[lane]   = a0;
    reinterpret_cast<float4*>(&sm_ctx[wave][256])[lane] = a1;
    if (lane == 0) { sm_m[wave] = m; sm_s[wave] = s; }
    __syncthreads();

    float M = -3.0e38f;
    #pragma unroll
    for (int i = 0; i < 16; ++i) M = fmaxf(M, sm_m[i]);
    float w[16];
    float S = 0.f;
    #pragma unroll
    for (int i = 0; i < 16; ++i) {
        w[i] = __expf(sm_m[i] - M);
        S += sm_s[i] * w[i];
    }
    const float inv = 1.0f / (S * (float)L_DIM);

    for (int d = tid; d < D_DIM; d += 1024) {
        float acc = 0.f;
        #pragma unroll
        for (int i = 0; i < 16; ++i) acc += sm_ctx[i][d] * w[i];
        out[(size_t)b * D_DIM + d] = acc * inv;
    }
}

extern "C" void kernel_launch(void* const* d_in, const int* in_sizes, int n_in,
                              void* d_out, int out_size, void* d_ws, size_t ws_size,
                              hipStream_t stream) {
    const float* h   = (const float*)d_in[0];  // [B, D]
    const float* enc = (const float*)d_in[1];  // [B, L, D]
    float* out = (float*)d_out;                // [B, D]

    // No d_ws usage at all: cross-block state lives transiently in `out`,
    // guarded by cooperative grid barriers.
    void* args[] = { (void*)&h, (void*)&enc, (void*)&out };
    hipError_t err = hipLaunchCooperativeKernel(
        reinterpret_cast<const void*>(&attn_fused_coop),
        dim3(CCHUNK, B_DIM), dim3(256), args, 0, stream);

    if (err != hipSuccess) {
        // Cooperative launch unavailable (e.g. capture restriction):
        // one block per batch, fully self-contained.
        attn_fallback<<<B_DIM, 1024, 0, stream>>>(h, enc, out);
    }
}

// Round 2
// 689.756 us; speedup vs baseline: 1.4306x; 1.4306x over previous
//
#include <hip/hip_runtime.h>

// B=64, L=4096, D=512, fp32.
// context[b,d] = (1/L) * sum_l softmax_l(energy[b,:]) * enc[b,l,d]
// energy[b,l]  = dot(h[b,:], enc[b,l,:])
//
// Two-pass, workspace-based (the 2-GiB ws poison fill is unconditional harness
// overhead -- round 1 proved avoiding ws doesn't remove it, and cooperative
// grid.sync() cost ~100us each. So: no cooperative launch, tiny fast kernels.)
//
// Round-2 change: INTERLEAVED row mapping. Previously each wave owned 64
// contiguous rows, so all 4096 waves started at 128-KiB-aligned addresses and
// advanced in lockstep -> HBM channel camping (~3.2 TB/s effective). Now wave
// g of batch b handles rows l = g + 128*r: at any instant the 128 waves of a
// batch read 128 CONSECUTIVE rows (a 256 KiB contiguous sliding window),
// spreading load over all channels. C raised 16->32 (2048 blocks, 32 waves/CU).

#define D_DIM 512
#define B_DIM 64
#define L_DIM 4096
#define C_CHUNK 32                     // chunks (blocks) per batch
#define WPB 4                          // waves per block
#define WAVES_PER_B (C_CHUNK * WPB)    // 128
#define ROWS_PER_WAVE (L_DIM / WAVES_PER_B)  // 32

__global__ __launch_bounds__(256, 8) void attn_pass1i(
    const float* __restrict__ h,      // [B, D]
    const float* __restrict__ enc,    // [B, L, D]
    float* __restrict__ part_ms,      // [B, C, 2]  (m, s)
    float* __restrict__ part_ctx)     // [B, C, D]
{
    const int b    = blockIdx.y;
    const int c    = blockIdx.x;
    const int tid  = threadIdx.x;
    const int wave = tid >> 6;
    const int lane = tid & 63;
    const int g    = c * WPB + wave;   // wave id within batch, 0..127

    // h fragment: lane covers d = 4*lane..4*lane+3 and 256+4*lane..+3
    const float4* h4 = reinterpret_cast<const float4*>(h + (size_t)b * D_DIM);
    const float4 h0 = h4[lane];
    const float4 h1 = h4[lane + 64];

    // interleaved rows: l = g + 128*r
    const float* rowp = enc + ((size_t)b * L_DIM + (size_t)g) * D_DIM + 4 * lane;
    const size_t rowStride = (size_t)WAVES_PER_B * D_DIM;  // 128 rows = 256 KiB

    float m = -3.0e38f;
    float s = 0.0f;
    float4 a0 = {0.f, 0.f, 0.f, 0.f};
    float4 a1 = {0.f, 0.f, 0.f, 0.f};

    float4 v0 = *reinterpret_cast<const float4*>(rowp);
    float4 v1 = *reinterpret_cast<const float4*>(rowp + 256);

    for (int r = 0; r < ROWS_PER_WAVE; ++r) {
        // prefetch next row (clamped: last iter re-reads current row, L1-hit)
        const float* np = rowp + ((r + 1 < ROWS_PER_WAVE) ? rowStride : 0);
        const float4 nv0 = *reinterpret_cast<const float4*>(np);
        const float4 nv1 = *reinterpret_cast<const float4*>(np + 256);

        float e = h0.x * v0.x + h0.y * v0.y + h0.z * v0.z + h0.w * v0.w
                + h1.x * v1.x + h1.y * v1.y + h1.z * v1.z + h1.w * v1.w;
        #pragma unroll
        for (int off = 32; off > 0; off >>= 1)
            e += __shfl_xor(e, off, 64);
        // e is wave-uniform; branch below is wave-uniform (taken ~ln(rows) times)
        if (e > m) {
            const float alpha = __expf(m - e);
            s *= alpha;
            a0.x *= alpha; a0.y *= alpha; a0.z *= alpha; a0.w *= alpha;
            a1.x *= alpha; a1.y *= alpha; a1.z *= alpha; a1.w *= alpha;
            m = e;
        }
        const float w = __expf(e - m);
        s += w;
        a0.x += w * v0.x; a0.y += w * v0.y; a0.z += w * v0.z; a0.w += w * v0.w;
        a1.x += w * v1.x; a1.y += w * v1.y; a1.z += w * v1.z; a1.w += w * v1.w;

        v0 = nv0; v1 = nv1;
        rowp += rowStride;
    }

    // ---- combine the 4 waves of this block in LDS ----
    __shared__ float sm_m[4];
    __shared__ float sm_s[4];
    __shared__ float sm_ctx[4][D_DIM];

    reinterpret_cast<float4*>(&sm_ctx[wave][0])[lane]   = a0;  // d = 4*lane
    reinterpret_cast<float4*>(&sm_ctx[wave][256])[lane] = a1;  // d = 256+4*lane
    if (lane == 0) { sm_m[wave] = m; sm_s[wave] = s; }
    __syncthreads();

    const float M  = fmaxf(fmaxf(sm_m[0], sm_m[1]), fmaxf(sm_m[2], sm_m[3]));
    const float w0 = __expf(sm_m[0] - M);
    const float w1 = __expf(sm_m[1] - M);
    const float w2 = __expf(sm_m[2] - M);
    const float w3 = __expf(sm_m[3] - M);

    if (tid == 0) {
        const float S = sm_s[0] * w0 + sm_s[1] * w1 + sm_s[2] * w2 + sm_s[3] * w3;
        float* ms = part_ms + ((size_t)b * C_CHUNK + c) * 2;
        ms[0] = M;
        ms[1] = S;
    }

    float* dst = part_ctx + ((size_t)b * C_CHUNK + c) * D_DIM;
    for (int d = tid; d < D_DIM; d += 256) {
        dst[d] = sm_ctx[0][d] * w0 + sm_ctx[1][d] * w1
               + sm_ctx[2][d] * w2 + sm_ctx[3][d] * w3;
    }
}

__global__ __launch_bounds__(256) void attn_pass2(
    const float* __restrict__ part_ms,   // [B, C, 2]
    const float* __restrict__ part_ctx,  // [B, C, D]
    float* __restrict__ out,             // [B, D]
    float invL)
{
    const int b   = blockIdx.x;
    const int tid = threadIdx.x;

    __shared__ float w_sm[C_CHUNK];
    __shared__ float invSL;

    if (tid == 0) {
        const float* ms = part_ms + (size_t)b * C_CHUNK * 2;
        float M = -3.0e38f;
        for (int i = 0; i < C_CHUNK; ++i) M = fmaxf(M, ms[2 * i]);
        float S = 0.f;
        for (int i = 0; i < C_CHUNK; ++i) {
            const float w = __expf(ms[2 * i] - M);
            w_sm[i] = w;
            S += w * ms[2 * i + 1];
        }
        invSL = invL / S;
    }
    __syncthreads();

    const float scale = invSL;
    for (int d = tid; d < D_DIM; d += 256) {
        float acc = 0.f;
        #pragma unroll 8
        for (int i = 0; i < C_CHUNK; ++i)
            acc += w_sm[i] * part_ctx[((size_t)b * C_CHUNK + i) * D_DIM + d];
        out[(size_t)b * D_DIM + d] = acc * scale;
    }
}

extern "C" void kernel_launch(void* const* d_in, const int* in_sizes, int n_in,
                              void* d_out, int out_size, void* d_ws, size_t ws_size,
                              hipStream_t stream) {
    const float* h   = (const float*)d_in[0];  // [B, D]
    const float* enc = (const float*)d_in[1];  // [B, L, D]
    float* out = (float*)d_out;                // [B, D]

    // Partials: [B, C, 2] + [B, C, D] floats = 64*32*514*4 B ~= 4.2 MB.
    float* part_ms  = (float*)d_ws;
    float* part_ctx = part_ms + (size_t)B_DIM * C_CHUNK * 2;  // 16B-aligned

    dim3 grid1(C_CHUNK, B_DIM);
    attn_pass1i<<<grid1, 256, 0, stream>>>(h, enc, part_ms, part_ctx);
    attn_pass2<<<B_DIM, 256, 0, stream>>>(part_ms, part_ctx, out,
                                          1.0f / (float)L_DIM);
}

// Round 4
// 677.749 us; speedup vs baseline: 1.4559x; 1.0177x over previous
//
#include <hip/hip_runtime.h>

// B=64, L=4096, D=512, fp32.
// context[b,d] = (1/L) * sum_l softmax_l(energy[b,:]) * enc[b,l,d]
// energy[b,l]  = dot(h[b,:], enc[b,l,:])
//
// Two-pass, workspace-based. Timed-graph tax (unconditional, not ours):
// 2-GiB ws poison fill ~330us + input restore ~195us. Our controllable part
// is pass1 (~142us in round 0 vs 85us read roofline).
//
// Round-4 = round-3 resubmit (container infra failure, no data): 4-ROW
// REGISTER GROUPS, ping-pong double buffered. Old loop kept only 2 KiB/wave
// in flight (one row) with a serial 6-step shuffle butterfly between loads
// -> ~3.6 TB/s effective. Now 8 dwordx4 loads issue back-to-back per group
// (8 KiB/wave outstanding) while the previous group's 4 independent
// butterflies compute (ILP), 4x fewer rescale checks / loop iterations.
// Contiguous per-wave row segments, C=16, 1024 blocks.

#define D_DIM 512
#define B_DIM 64
#define L_DIM 4096
#define C_CHUNK 16                       // chunks (blocks) per batch
#define WPB 4                            // waves per block
#define ROWS_PER_WAVE (L_DIM / (C_CHUNK * WPB))  // 64
#define GRP 4                            // rows per register group
#define NGRP (ROWS_PER_WAVE / GRP)       // 16

struct Row { float4 lo, hi; };

__device__ __forceinline__ float dot8(const float4 h0, const float4 h1,
                                      const float4 v0, const float4 v1) {
    return h0.x * v0.x + h0.y * v0.y + h0.z * v0.z + h0.w * v0.w
         + h1.x * v1.x + h1.y * v1.y + h1.z * v1.z + h1.w * v1.w;
}

__device__ __forceinline__ void load_group(Row (&buf)[GRP], const float* p) {
    #pragma unroll
    for (int i = 0; i < GRP; ++i) {
        buf[i].lo = *reinterpret_cast<const float4*>(p + i * D_DIM);
        buf[i].hi = *reinterpret_cast<const float4*>(p + i * D_DIM + 256);
    }
}

__device__ __forceinline__ void process_group(
    const Row (&buf)[GRP], const float4 h0, const float4 h1,
    float& m, float& s, float4& a0, float4& a1)
{
    float e[GRP];
    #pragma unroll
    for (int i = 0; i < GRP; ++i)
        e[i] = dot8(h0, h1, buf[i].lo, buf[i].hi);

    // 4 independent butterflies, interleaved (ILP hides shuffle latency)
    #pragma unroll
    for (int off = 32; off > 0; off >>= 1) {
        #pragma unroll
        for (int i = 0; i < GRP; ++i)
            e[i] += __shfl_xor(e[i], off, 64);
    }

    const float gm = fmaxf(fmaxf(e[0], e[1]), fmaxf(e[2], e[3]));
    // wave-uniform branch (e[i] are wave-uniform after the full butterfly)
    if (gm > m) {
        const float alpha = __expf(m - gm);
        s *= alpha;
        a0.x *= alpha; a0.y *= alpha; a0.z *= alpha; a0.w *= alpha;
        a1.x *= alpha; a1.y *= alpha; a1.z *= alpha; a1.w *= alpha;
        m = gm;
    }

    float w[GRP];
    float ws = 0.f;
    #pragma unroll
    for (int i = 0; i < GRP; ++i) { w[i] = __expf(e[i] - m); ws += w[i]; }
    s += ws;

    #pragma unroll
    for (int i = 0; i < GRP; ++i) {
        a0.x += w[i] * buf[i].lo.x; a0.y += w[i] * buf[i].lo.y;
        a0.z += w[i] * buf[i].lo.z; a0.w += w[i] * buf[i].lo.w;
        a1.x += w[i] * buf[i].hi.x; a1.y += w[i] * buf[i].hi.y;
        a1.z += w[i] * buf[i].hi.z; a1.w += w[i] * buf[i].hi.w;
    }
}

__global__ __launch_bounds__(256, 4) void attn_pass1g(
    const float* __restrict__ h,      // [B, D]
    const float* __restrict__ enc,    // [B, L, D]
    float* __restrict__ part_ms,      // [B, C, 2]  (m, s)
    float* __restrict__ part_ctx)     // [B, C, D]
{
    const int b    = blockIdx.y;
    const int c    = blockIdx.x;
    const int tid  = threadIdx.x;
    const int wave = tid >> 6;
    const int lane = tid & 63;

    const int l0 = c * (L_DIM / C_CHUNK) + wave * ROWS_PER_WAVE;

    // h fragment: lane covers d = 4*lane..4*lane+3 and 256+4*lane..+3
    const float4* h4 = reinterpret_cast<const float4*>(h + (size_t)b * D_DIM);
    const float4 h0 = h4[lane];
    const float4 h1 = h4[lane + 64];

    const float* base = enc + ((size_t)b * L_DIM + (size_t)l0) * D_DIM + 4 * lane;
    const size_t gstride = (size_t)GRP * D_DIM;   // 4 rows = 8 KiB

    float m = -3.0e38f;
    float s = 0.0f;
    float4 a0 = {0.f, 0.f, 0.f, 0.f};
    float4 a1 = {0.f, 0.f, 0.f, 0.f};

    Row bufA[GRP], bufB[GRP];
    load_group(bufA, base);                           // group 0

    for (int g = 0; g < NGRP - 2; g += 2) {
        load_group(bufB, base + (size_t)(g + 1) * gstride);
        process_group(bufA, h0, h1, m, s, a0, a1);    // group g
        load_group(bufA, base + (size_t)(g + 2) * gstride);
        process_group(bufB, h0, h1, m, s, a0, a1);    // group g+1
    }
    // tail: groups NGRP-2, NGRP-1
    load_group(bufB, base + (size_t)(NGRP - 1) * gstride);
    process_group(bufA, h0, h1, m, s, a0, a1);
    process_group(bufB, h0, h1, m, s, a0, a1);

    // ---- combine the 4 waves of this block in LDS ----
    __shared__ float sm_m[4];
    __shared__ float sm_s[4];
    __shared__ float sm_ctx[4][D_DIM];

    reinterpret_cast<float4*>(&sm_ctx[wave][0])[lane]   = a0;  // d = 4*lane
    reinterpret_cast<float4*>(&sm_ctx[wave][256])[lane] = a1;  // d = 256+4*lane
    if (lane == 0) { sm_m[wave] = m; sm_s[wave] = s; }
    __syncthreads();

    const float M  = fmaxf(fmaxf(sm_m[0], sm_m[1]), fmaxf(sm_m[2], sm_m[3]));
    const float w0 = __expf(sm_m[0] - M);
    const float w1 = __expf(sm_m[1] - M);
    const float w2 = __expf(sm_m[2] - M);
    const float w3 = __expf(sm_m[3] - M);

    if (tid == 0) {
        const float S = sm_s[0] * w0 + sm_s[1] * w1 + sm_s[2] * w2 + sm_s[3] * w3;
        float* ms = part_ms + ((size_t)b * C_CHUNK + c) * 2;
        ms[0] = M;
        ms[1] = S;
    }

    float* dst = part_ctx + ((size_t)b * C_CHUNK + c) * D_DIM;
    for (int d = tid; d < D_DIM; d += 256) {
        dst[d] = sm_ctx[0][d] * w0 + sm_ctx[1][d] * w1
               + sm_ctx[2][d] * w2 + sm_ctx[3][d] * w3;
    }
}

__global__ __launch_bounds__(256) void attn_pass2(
    const float* __restrict__ part_ms,   // [B, C, 2]
    const float* __restrict__ part_ctx,  // [B, C, D]
    float* __restrict__ out,             // [B, D]
    float invL)
{
    const int b   = blockIdx.x;
    const int tid = threadIdx.x;

    __shared__ float w_sm[C_CHUNK];
    __shared__ float invSL;

    if (tid == 0) {
        const float* ms = part_ms + (size_t)b * C_CHUNK * 2;
        float M = -3.0e38f;
        for (int i = 0; i < C_CHUNK; ++i) M = fmaxf(M, ms[2 * i]);
        float S = 0.f;
        for (int i = 0; i < C_CHUNK; ++i) {
            const float w = __expf(ms[2 * i] - M);
            w_sm[i] = w;
            S += w * ms[2 * i + 1];
        }
        invSL = invL / S;
    }
    __syncthreads();

    const float scale = invSL;
    for (int d = tid; d < D_DIM; d += 256) {
        float acc = 0.f;
        #pragma unroll
        for (int i = 0; i < C_CHUNK; ++i)
            acc += w_sm[i] * part_ctx[((size_t)b * C_CHUNK + i) * D_DIM + d];
        out[(size_t)b * D_DIM + d] = acc * scale;
    }
}

extern "C" void kernel_launch(void* const* d_in, const int* in_sizes, int n_in,
                              void* d_out, int out_size, void* d_ws, size_t ws_size,
                              hipStream_t stream) {
    const float* h   = (const float*)d_in[0];  // [B, D]
    const float* enc = (const float*)d_in[1];  // [B, L, D]
    float* out = (float*)d_out;                // [B, D]

    // Partials: [B, C, 2] + [B, C, D] floats ~= 2.1 MB.
    float* part_ms  = (float*)d_ws;
    float* part_ctx = part_ms + (size_t)B_DIM * C_CHUNK * 2;  // 16B-aligned

    dim3 grid1(C_CHUNK, B_DIM);
    attn_pass1g<<<grid1, 256, 0, stream>>>(h, enc, part_ms, part_ctx);
    attn_pass2<<<B_DIM, 256, 0, stream>>>(part_ms, part_ctx, out,
                                          1.0f / (float)L_DIM);
}